// Round 4
// baseline (3113.058 us; speedup 1.0000x reference)
//
#include <hip/hip_runtime.h>
#include <stdint.h>

#define B_ 128
#define T_ 2048
#define I_ 256
#define H_ 256

// ---------- gate helpers (overflow-safe, fp32) ----------

__device__ __forceinline__ void gates_sg(float z, float& s, float& g){
  float az = fabsf(z);
  float a  = __expf(-az);                          // in (0,1]
  float r1 = __builtin_amdgcn_rcpf(1.0f + a);
  s = (z >= 0.0f) ? r1 : a * r1;                   // sigmoid(z)
  float a2 = a * a;
  float gm = (1.0f - a2) * __builtin_amdgcn_rcpf(1.0f + a2);
  g = (z >= 0.0f) ? gm : -gm;                      // tanh(z)
}
__device__ __forceinline__ float tanh_stable(float c){
  float ac = fabsf(c);
  float u  = __expf(-2.0f * ac);                   // underflows to 0, never Inf
  float tm = (1.0f - u) * __builtin_amdgcn_rcpf(1.0f + u);
  return (c >= 0.0f) ? tm : -tm;
}

// DPP quad_perm butterfly (in-register, no LDS): 0xB1 = lane^1
template<int CTRL>
__device__ __forceinline__ float dpp_qperm(float v){
  return __builtin_bit_cast(float,
      __builtin_amdgcn_update_dpp(0, __builtin_bit_cast(int, v), CTRL, 0xF, 0xF, true));
}

#define FMA4(hs, wv, ax, ay, az, aw)            \
  ax = fmaf(hs, wv.x, ax); ay = fmaf(hs, wv.y, ay); \
  az = fmaf(hs, wv.z, az); aw = fmaf(hs, wv.w, aw);

// ---------- phase 1: xp[b, j, t] = x[b,t,:] @ w_x[:,j] + b_x[j] + b_h[j]  (fp32, [B,H,Tc]) ----------
// (unchanged — isolate the rec_k full-dot restructure)

__global__ __launch_bounds__(512, 2) void xproj_k(
    const float* __restrict__ x, const float* __restrict__ w_x,
    const float* __restrict__ b_x, const float* __restrict__ b_h,
    float* __restrict__ xp, int t0c, int Tc)
{
  const int tid  = threadIdx.x;
  const int wv   = tid >> 6;
  const int lane = tid & 63;
  const int ks   = wv * 32;

  float4 w4[32];                                   // col-slice of w_x
  #pragma unroll
  for (int kk = 0; kk < 32; ++kk)
    w4[kk] = *(const float4*)&w_x[(ks + kk) * H_ + 4 * lane];

  float bias = 0.0f;
  if (tid < 256) bias = b_x[tid] + b_h[tid];

  __shared__ float4 xs4[256];                      // 4 rows x 256 floats (4 KB)
  __shared__ float  pb[8][4][256];                 // [wave][row][col] (32 KB)

  const int rows_per_b = Tc >> 2;                  // 4-row blocks per batch row
  const int nblk  = (B_ * Tc) >> 2;
  const int iters = (nblk + gridDim.x - 1) / gridDim.x;
  const int bid0  = blockIdx.x * iters;            // contiguous range [bid0, bid0+iters)

  float4 r = make_float4(0,0,0,0);                 // prefetch register
  if (tid < 256 && bid0 < nblk){
    const int b  = bid0 / rows_per_b;
    const int t4 = (bid0 - b * rows_per_b) << 2;
    r = ((const float4*)x)[ (int64_t)(b * T_ + t0c + t4) * 64 + tid ];
  }

  for (int i = 0; i < iters; ++i){
    const int bid = bid0 + i;
    const bool valid = bid < nblk;
    if (tid < 256 && valid) xs4[tid] = r;          // stage current tile
    __syncthreads();                               // tile visible to all waves
    if (tid < 256 && bid + 1 < nblk){              // prefetch next tile
      const int bn = bid + 1;
      const int b  = bn / rows_per_b;
      const int t4 = (bn - b * rows_per_b) << 2;
      r = ((const float4*)x)[ (int64_t)(b * T_ + t0c + t4) * 64 + tid ];
    }
    if (valid){
      #pragma unroll
      for (int rr = 0; rr < 4; ++rr){
        const float4* xr = &xs4[rr * 64 + (ks >> 2)];
        float ax = 0.f, ay = 0.f, az = 0.f, aw = 0.f;
        #pragma unroll
        for (int q = 0; q < 8; ++q){
          float4 hv = xr[q];                       // broadcast read
          FMA4(hv.x, w4[4*q+0], ax, ay, az, aw);
          FMA4(hv.y, w4[4*q+1], ax, ay, az, aw);
          FMA4(hv.z, w4[4*q+2], ax, ay, az, aw);
          FMA4(hv.w, w4[4*q+3], ax, ay, az, aw);
        }
        *(float4*)&pb[wv][rr][4*lane] = make_float4(ax, ay, az, aw);
      }
    }
    __syncthreads();                               // partials ready; xs4 consumed
    if (valid && tid < 256){
      const int b  = bid / rows_per_b;
      const int t4 = (bid - b * rows_per_b) << 2;
      float z0 = bias, z1 = bias, z2 = bias, z3 = bias;
      #pragma unroll
      for (int w = 0; w < 8; ++w){
        z0 += pb[w][0][tid]; z1 += pb[w][1][tid];
        z2 += pb[w][2][tid]; z3 += pb[w][3][tid];
      }
      *(float4*)&xp[ ((int64_t)b * H_ + tid) * Tc + t4 ] = make_float4(z0, z1, z2, z3);
    }
  }
}

// ---------- phase 2 ("full-dot"): no partial-sum LDS round-trip ----------
// 512 thr / 8 waves. Wave w owns FULL columns [32w,32w+32); lane pair (l, l^1)
// splits one column's K=256 dot: lane k-half s=l&1 covers k in [128s,128s+128).
// Weights: 32 float4/lane (128 vals -> AGPR-resident, VALU reads AGPRs free).
// Per step: 32x ds_read_b128 h-broadcast (pipelines under 128 FMAs) ->
// 1 DPP quad_perm pair-reduce (in-register) -> gates in ALL 64 lanes
// (pair-redundant, IEEE-identical) -> even lanes ds_write h (32 banks,
// conflict-free) -> ONE barrier. LDS: 2 KB (was 33 KB). xp prefetch issued
// right after a barrier so the next barrier's implicit vmcnt(0) doesn't
// drain an in-flight HBM load.

__global__ __launch_bounds__(512, 2) void rec_k(
    const float* __restrict__ xp, const float* __restrict__ w_h,
    float* __restrict__ out, int Tc, int init)
{
  const int tid = threadIdx.x;
  const int w   = tid >> 6;
  const int l   = tid & 63;
  const int s   = l & 1;                 // k-half
  const int c   = 32 * w + (l >> 1);     // owned column (pairwise redundant)
  const int b   = blockIdx.x;
  const int k0  = 128 * s;

  // wreg[q] = W[k0+4q .. k0+4q+3][c] — scalar loads, coalesced across lanes
  float4 wreg[32];
  #pragma unroll
  for (int q = 0; q < 32; ++q){
    wreg[q].x = w_h[(k0 + 4*q + 0) * H_ + c];
    wreg[q].y = w_h[(k0 + 4*q + 1) * H_ + c];
    wreg[q].z = w_h[(k0 + 4*q + 2) * H_ + c];
    wreg[q].w = w_h[(k0 + 4*q + 3) * H_ + c];
  }

  __shared__ float hlds[2][H_];          // double-buffered h (2 KB)

  float cst = 0.f, hcur = 0.f;
  if (!init){
    hcur = out[(int64_t)b * H_ + c];
    cst  = out[(int64_t)B_ * H_ + (int64_t)b * H_ + c];
  }
  if (s == 0) hlds[0][c] = hcur;
  __syncthreads();

  const float* xpr = xp + ((int64_t)b * H_ + c) * Tc;
  float4 xq = *(const float4*)xpr;       // prefetch t=0..3

  int pp = 0;
  for (int t = 0; t < Tc; t += 4){
    float xa[4] = {xq.x, xq.y, xq.z, xq.w};
    // issue next prefetch immediately after the previous barrier: ~1 full
    // step (~1000cy) before the next vmcnt(0) drain -> latency hidden
    if (t + 4 < Tc) xq = *(const float4*)(xpr + t + 4);
    #pragma unroll
    for (int tt = 0; tt < 4; ++tt){
      // ---- matvec: K=128 half-dot, h streamed from LDS broadcast ----
      const float4* h4 = (const float4*)&hlds[pp][k0];
      float ax = 0.f, ay = 0.f, az = 0.f, aw = 0.f;
      #pragma unroll
      for (int q = 0; q < 32; ++q){
        float4 hv = h4[q];               // 2-group broadcast read
        ax = fmaf(hv.x, wreg[q].x, ax);  // 4 rotating accumulators:
        ay = fmaf(hv.y, wreg[q].y, ay);  // 8cy reuse gap > 4cy fma latency
        az = fmaf(hv.z, wreg[q].z, az);
        aw = fmaf(hv.w, wreg[q].w, aw);
      }
      float sum = (ax + ay) + (az + aw);
      sum += dpp_qperm<0xB1>(sum);       // + lane^1 : full K=256 dot
      float z = xa[tt] + sum;
      float sg, gg; gates_sg(z, sg, gg);
      cst  = sg * (cst + gg);
      hcur = sg * tanh_stable(cst);
      if (s == 0) hlds[pp ^ 1][c] = hcur;  // 32 lanes -> 32 banks, conflict-free
      __syncthreads();                     // the ONLY barrier per step
      pp ^= 1;
    }
  }
  if (s == 0){
    out[(int64_t)b * H_ + c] = hcur;                       // h_T
    out[(int64_t)B_ * H_ + (int64_t)b * H_ + c] = cst;     // c_T
  }
}

// ---------- insurance fallback: fused, no workspace (not expected to run) ----------

__global__ __launch_bounds__(512, 2) void lstm_fused_k(
    const float* __restrict__ x, const float* __restrict__ w_x,
    const float* __restrict__ b_x, const float* __restrict__ w_h,
    const float* __restrict__ b_h, float* __restrict__ out)
{
  const int tid  = threadIdx.x;
  const int wv   = tid >> 6;
  const int lane = tid & 63;
  const int ks   = wv * 32;
  const int b    = blockIdx.x;

  float4 wh4[32], wx4[32];
  #pragma unroll
  for (int kk = 0; kk < 32; ++kk){
    wh4[kk] = *(const float4*)&w_h[(ks + kk) * H_ + 4 * lane];
    wx4[kk] = *(const float4*)&w_x[(ks + kk) * H_ + 4 * lane];
  }
  float bias = 0.0f;
  if (tid < 256) bias = b_x[tid] + b_h[tid];

  __shared__ float hb[2][H_];
  __shared__ float4 xs4[2][64];
  __shared__ float pbuf[8][H_];
  const float* xrow = x + (int64_t)b * T_ * I_;
  if (tid < 256) hb[0][tid] = 0.f;
  if (tid < 64)  xs4[0][tid] = ((const float4*)xrow)[tid];
  __syncthreads();
  float c = 0.f, hn = 0.f;
  int p = 0;
  for (int t = 0; t < T_; ++t){
    const float4* hr = (const float4*)&hb[p][ks];
    const float4* xr = &xs4[p][ks >> 2];
    float ax = 0.f, ay = 0.f, az = 0.f, aw = 0.f;
    #pragma unroll
    for (int q = 0; q < 8; ++q){
      float4 hv = hr[q];
      FMA4(hv.x, wh4[4*q+0], ax, ay, az, aw);
      FMA4(hv.y, wh4[4*q+1], ax, ay, az, aw);
      FMA4(hv.z, wh4[4*q+2], ax, ay, az, aw);
      FMA4(hv.w, wh4[4*q+3], ax, ay, az, aw);
    }
    #pragma unroll
    for (int q = 0; q < 8; ++q){
      float4 xv = xr[q];
      FMA4(xv.x, wx4[4*q+0], ax, ay, az, aw);
      FMA4(xv.y, wx4[4*q+1], ax, ay, az, aw);
      FMA4(xv.z, wx4[4*q+2], ax, ay, az, aw);
      FMA4(xv.w, wx4[4*q+3], ax, ay, az, aw);
    }
    *(float4*)&pbuf[wv][4*lane] = make_float4(ax, ay, az, aw);
    __syncthreads();
    if (tid < 256){
      float z = bias
              + ((pbuf[0][tid] + pbuf[1][tid]) + (pbuf[2][tid] + pbuf[3][tid]))
              + ((pbuf[4][tid] + pbuf[5][tid]) + (pbuf[6][tid] + pbuf[7][tid]));
      float s, g; gates_sg(z, s, g);
      c  = s * (c + g);
      hn = s * tanh_stable(c);
      hb[p ^ 1][tid] = hn;
    } else if (tid < 320 && t + 1 < T_){
      xs4[p ^ 1][tid - 256] = ((const float4*)(xrow + (int64_t)(t + 1) * I_))[tid - 256];
    }
    __syncthreads();
    p ^= 1;
  }
  if (tid < 256){
    out[(int64_t)b * H_ + tid] = hn;
    out[(int64_t)B_ * H_ + (int64_t)b * H_ + tid] = c;
  }
}

// ---------- launch ----------

extern "C" void kernel_launch(void* const* d_in, const int* in_sizes, int n_in,
                              void* d_out, int out_size, void* d_ws, size_t ws_size,
                              hipStream_t stream)
{
  const float* x   = (const float*)d_in[0];
  const float* w_x = (const float*)d_in[1];
  const float* b_x = (const float*)d_in[2];
  const float* w_h = (const float*)d_in[3];
  const float* b_h = (const float*)d_in[4];
  float* out = (float*)d_out;

  const size_t per_t = (size_t)B_ * H_ * sizeof(float);   // bytes of xp per timestep
  int Tc_max = (int)((ws_size / per_t) & ~(size_t)3);
  if (Tc_max >= 4){
    if (Tc_max > T_) Tc_max = T_;
    int done = 0, first = 1;
    while (done < T_){
      int Tc = (T_ - done < Tc_max) ? (T_ - done) : Tc_max;
      xproj_k<<<512, 512, 0, stream>>>(x, w_x, b_x, b_h, (float*)d_ws, done, Tc);
      rec_k<<<128, 512, 0, stream>>>((const float*)d_ws, w_h, out, Tc, first);
      done += Tc; first = 0;
    }
  } else {
    lstm_fused_k<<<128, 512, 0, stream>>>(x, w_x, b_x, w_h, b_h, out);
  }
}